// Round 1
// baseline (111.329 us; speedup 1.0000x reference)
//
#include <hip/hip_runtime.h>

#define EPS 1e-3f

typedef float f32x4 __attribute__((ext_vector_type(4)));
typedef float f4    __attribute__((ext_vector_type(4)));
typedef short short8 __attribute__((ext_vector_type(8)));

__device__ __forceinline__ unsigned short f2bf(float f) {
    unsigned u = __float_as_uint(f);
    u += 0x7FFFu + ((u >> 16) & 1u);   // round-to-nearest-even
    return (unsigned short)(u >> 16);
}
__device__ __forceinline__ float bf2f(unsigned s) {
    return __uint_as_float(s << 16);
}

// ---------------------------------------------------------------------------
// Prep: fold BN1/BN2 into attention weights, transpose all weights to bf16
//   w3T  [F=256][C=256] bf16 : w3T[f][c]  = w3[c][f]
//   wa1T [A=32 ][C=256] bf16 : wa1T[a][c] = w_a1[c][a] * g1[c]*rsqrt(v1[c]+eps)
//   wa2T [F=256][A=32 ] bf16 : wa2T[f][a] = w_a2[a][f] * g2[a]*rsqrt(v2[a]+eps)
//   b_a1p[a] = b_a1[a] + sum_c (be1[c]-m1[c]*s1[c]) * w_a1[c][a]
//   b_a2p[f] = b_a2[f] + sum_a (be2[a]-m2[a]*s2[a]) * w_a2[a][f]
// ---------------------------------------------------------------------------
__global__ void prep_kernel(const float* __restrict__ w3,
                            const float* __restrict__ g1, const float* __restrict__ be1,
                            const float* __restrict__ m1, const float* __restrict__ v1,
                            const float* __restrict__ wa1, const float* __restrict__ ba1,
                            const float* __restrict__ g2, const float* __restrict__ be2,
                            const float* __restrict__ m2, const float* __restrict__ v2,
                            const float* __restrict__ wa2, const float* __restrict__ ba2,
                            unsigned short* __restrict__ w3T,
                            unsigned short* __restrict__ wa1T,
                            unsigned short* __restrict__ wa2T,
                            float* __restrict__ b_a1p, float* __restrict__ b_a2p)
{
    const int blk = blockIdx.x;
    const int tid = threadIdx.x;
    if (blk < 64) {
        // transpose w3 -> w3T, 4 f-rows per block
        #pragma unroll
        for (int i = 0; i < 4; ++i) {
            int f = blk * 4 + i;
            w3T[f * 256 + tid] = f2bf(w3[tid * 256 + f]);
        }
    } else if (blk < 96) {
        int a = blk - 64;
        int c = tid;
        float s1 = rsqrtf(v1[c] + EPS) * g1[c];
        float wv = wa1[c * 32 + a];
        wa1T[a * 256 + c] = f2bf(wv * s1);
        float part = (be1[c] - m1[c] * s1) * wv;
        __shared__ float red[4];
        #pragma unroll
        for (int off = 32; off > 0; off >>= 1) part += __shfl_down(part, off);
        if ((tid & 63) == 0) red[tid >> 6] = part;
        __syncthreads();
        if (tid == 0) b_a1p[a] = ba1[a] + red[0] + red[1] + red[2] + red[3];
    } else {
        int f = tid;
        float acc = ba2[f];
        #pragma unroll
        for (int a = 0; a < 32; ++a) {
            float s2 = rsqrtf(v2[a] + EPS) * g2[a];
            float wv = wa2[a * 256 + f];
            wa2T[f * 32 + a] = f2bf(wv * s2);
            acc += (be2[a] - m2[a] * s2) * wv;
        }
        b_a2p[f] = acc;
    }
}

// ---------------------------------------------------------------------------
// Fused main kernel. One block = one image row (b,h): 64 pixels, 256 ch.
// 4 waves x 16 pixels each.  LDS: xbf[64][256] bf16 (x row, for attention A),
// rs[64][256] bf16 (3-row vertical sum -> rewritten in place to full 3x3 sum).
// Both XOR-swizzled: byte = row*512 + (cb ^ ((row&7)<<4)).
// ---------------------------------------------------------------------------
__global__ __launch_bounds__(256, 2)
void fused_kernel(const float* __restrict__ x, const float* __restrict__ b3,
                  const unsigned short* __restrict__ w3T,
                  const unsigned short* __restrict__ wa1T,
                  const unsigned short* __restrict__ wa2T,
                  const float* __restrict__ b_a1p, const float* __restrict__ b_a2p,
                  float* __restrict__ out)
{
    __shared__ __align__(16) unsigned char lds[65536];
    // region 0: xbf  [0, 32768)
    // region 1: rs   [32768, 65536)

    const int tid = threadIdx.x;
    const int bid = blockIdx.x;
    // XCD-aware swizzle: 1024 blocks, 8 XCDs -> 128 consecutive rows per XCD
    const int swz = (bid & 7) * 128 + (bid >> 3);
    const int b = swz >> 6;
    const int h = swz & 63;

    const float* xrow = x + ((size_t)(b * 64 + h) * 64) * 256;
    const bool hm = (h > 0), hp = (h < 63);
    const f4* p0 = (const f4*)xrow;
    const f4* pm = (const f4*)(xrow - 64 * 256);
    const f4* pp = (const f4*)(xrow + 64 * 256);
    const f4 zero4 = {0.f, 0.f, 0.f, 0.f};

    // ---------------- phase 0: stage x row (bf16) + vertical 3-row sum ------
    #pragma unroll 4
    for (int j = 0; j < 16; ++j) {
        int v  = tid + j * 256;        // float4 index within the row (0..4095)
        int w  = v >> 6;
        int c4 = v & 63;
        f4 a0 = p0[v];
        f4 am = hm ? pm[v] : zero4;
        f4 ap = hp ? pp[v] : zero4;
        unsigned cb   = (unsigned)c4 * 8u;
        unsigned addr = (unsigned)w * 512u + (cb ^ (((unsigned)w & 7u) << 4));
        uint2 pk;
        pk.x = (unsigned)f2bf(a0.x) | ((unsigned)f2bf(a0.y) << 16);
        pk.y = (unsigned)f2bf(a0.z) | ((unsigned)f2bf(a0.w) << 16);
        *(uint2*)(lds + addr) = pk;
        f4 s = a0 + am + ap;
        uint2 pr;
        pr.x = (unsigned)f2bf(s.x) | ((unsigned)f2bf(s.y) << 16);
        pr.y = (unsigned)f2bf(s.z) | ((unsigned)f2bf(s.w) << 16);
        *(uint2*)(lds + 32768 + addr) = pr;
    }
    __syncthreads();

    // ---------------- phase 0.5: horizontal 3-tap sum in place (rs -> xs) ---
    {
        const int w05 = tid >> 2;      // pixel 0..63
        const int cs  = tid & 3;       // channel quarter
        #pragma unroll
        for (int ch = 0; ch < 2; ++ch) {
            uint2 tv[8];
            #pragma unroll
            for (int j = 0; j < 8; ++j) {
                int c4 = cs * 16 + ch * 8 + j;
                unsigned cb = (unsigned)c4 * 8u;
                f4 sum = zero4;
                #pragma unroll
                for (int dw = -1; dw <= 1; ++dw) {
                    int rw = w05 + dw;
                    if (rw >= 0 && rw < 64) {
                        unsigned ad = 32768u + (unsigned)rw * 512u +
                                      (cb ^ (((unsigned)rw & 7u) << 4));
                        uint2 q = *(const uint2*)(lds + ad);
                        sum.x += bf2f(q.x & 0xffffu);
                        sum.y += bf2f(q.x >> 16);
                        sum.z += bf2f(q.y & 0xffffu);
                        sum.w += bf2f(q.y >> 16);
                    }
                }
                uint2 pk;
                pk.x = (unsigned)f2bf(sum.x) | ((unsigned)f2bf(sum.y) << 16);
                pk.y = (unsigned)f2bf(sum.z) | ((unsigned)f2bf(sum.w) << 16);
                tv[j] = pk;
            }
            __syncthreads();
            #pragma unroll
            for (int j = 0; j < 8; ++j) {
                int c4 = cs * 16 + ch * 8 + j;
                unsigned cb = (unsigned)c4 * 8u;
                unsigned ad = 32768u + (unsigned)w05 * 512u +
                              (cb ^ (((unsigned)w05 & 7u) << 4));
                *(uint2*)(lds + ad) = tv[j];
            }
            __syncthreads();
        }
    }

    // ---------------- MFMA setup -------------------------------------------
    const int wv   = tid >> 6;
    const int lane = tid & 63;
    const int lrow = lane & 15;   // A-row (pixel) / B-col
    const int lkg  = lane >> 4;   // k-group
    const int pxb  = wv * 16;

    const int      arow  = pxb + lrow;
    const unsigned abase = (unsigned)arow * 512u;
    const unsigned aswz  = ((unsigned)arow & 7u) << 4;

    // ---------------- phase 1: attention GEMM1 (x_bn @ wa1') ---------------
    f32x4 acc1[2];
    acc1[0] = (f32x4){0,0,0,0};
    acc1[1] = (f32x4){0,0,0,0};
    #pragma unroll
    for (int kk = 0; kk < 8; ++kk) {
        unsigned cb = (unsigned)kk * 64u + (unsigned)lkg * 16u;
        short8 afr = *(const short8*)(lds + abase + (cb ^ aswz));
        #pragma unroll
        for (int t = 0; t < 2; ++t) {
            short8 bfr = *(const short8*)(wa1T + ((t * 16 + lrow) * 256 + kk * 32 + lkg * 8));
            acc1[t] = __builtin_amdgcn_mfma_f32_16x16x32_bf16(afr, bfr, acc1[t], 0, 0, 0);
        }
    }
    // bias + relu, stash a1 (bf16) in this wave's own xbf rows (done reading them)
    const unsigned a1base = (unsigned)wv * 8192u;
    #pragma unroll
    for (int t = 0; t < 2; ++t) {
        int col = t * 16 + lrow;
        float bb = b_a1p[col];
        #pragma unroll
        for (int r = 0; r < 4; ++r) {
            float vv = acc1[t][r] + bb;
            vv = vv > 0.f ? vv : 0.f;
            int row = lkg * 4 + r;
            *(unsigned short*)(lds + a1base + row * 64 + col * 2) = f2bf(vv);
        }
    }
    __syncthreads();

    // ---------------- phase 2: attention GEMM2 + softmax -------------------
    short8 a2fr = *(const short8*)(lds + a1base + lrow * 64 + lkg * 16);
    f32x4 att[16];
    #pragma unroll
    for (int t = 0; t < 16; ++t) {
        short8 bfr = *(const short8*)(wa2T + ((t * 16 + lrow) * 32 + lkg * 8));
        f32x4 z = {0,0,0,0};
        att[t] = __builtin_amdgcn_mfma_f32_16x16x32_bf16(a2fr, bfr, z, 0, 0, 0);
    }
    #pragma unroll
    for (int t = 0; t < 16; ++t) {
        float bb = b_a2p[t * 16 + lrow];
        #pragma unroll
        for (int r = 0; r < 4; ++r) {
            float vv = att[t][r] + bb;
            att[t][r] = vv > 0.f ? vv : 0.f;
        }
    }
    #pragma unroll
    for (int r = 0; r < 4; ++r) {
        float mx = att[0][r];
        #pragma unroll
        for (int t = 1; t < 16; ++t) mx = fmaxf(mx, att[t][r]);
        mx = fmaxf(mx, __shfl_xor(mx, 1));
        mx = fmaxf(mx, __shfl_xor(mx, 2));
        mx = fmaxf(mx, __shfl_xor(mx, 4));
        mx = fmaxf(mx, __shfl_xor(mx, 8));
        float sm = 0.f;
        #pragma unroll
        for (int t = 0; t < 16; ++t) {
            float e = __expf(att[t][r] - mx);
            att[t][r] = e;
            sm += e;
        }
        sm += __shfl_xor(sm, 1);
        sm += __shfl_xor(sm, 2);
        sm += __shfl_xor(sm, 4);
        sm += __shfl_xor(sm, 8);
        float inv = 1.f / sm;
        #pragma unroll
        for (int t = 0; t < 16; ++t) att[t][r] *= inv;
    }

    // ---------------- phase 3: main GEMM (xs @ w3) -------------------------
    f32x4 accs[16];
    #pragma unroll
    for (int t = 0; t < 16; ++t) accs[t] = (f32x4){0,0,0,0};
    #pragma unroll
    for (int kk = 0; kk < 8; ++kk) {
        unsigned cb = (unsigned)kk * 64u + (unsigned)lkg * 16u;
        short8 afr = *(const short8*)(lds + 32768 + abase + (cb ^ aswz));
        #pragma unroll
        for (int t = 0; t < 16; ++t) {
            short8 bfr = *(const short8*)(w3T + ((t * 16 + lrow) * 256 + kk * 32 + lkg * 8));
            accs[t] = __builtin_amdgcn_mfma_f32_16x16x32_bf16(afr, bfr, accs[t], 0, 0, 0);
        }
    }

    // ---------------- epilogue: out = aw * (s + cnt*b3) --------------------
    const int rh = (h == 0 || h == 63) ? 2 : 3;
    const size_t obase = ((size_t)(b * 64 + h) * 64) * 256;
    #pragma unroll
    for (int r = 0; r < 4; ++r) {
        int pxl = lkg * 4 + r;
        int px  = pxb + pxl;
        int rww = (px == 0 || px == 63) ? 2 : 3;
        float cnt = (float)(rh * rww);
        #pragma unroll
        for (int t = 0; t < 16; ++t) {
            int col = t * 16 + lrow;
            float sv = accs[t][r] + cnt * b3[col];
            out[obase + (size_t)px * 256 + col] = att[t][r] * sv;
        }
    }
}

extern "C" void kernel_launch(void* const* d_in, const int* in_sizes, int n_in,
                              void* d_out, int out_size, void* d_ws, size_t ws_size,
                              hipStream_t stream)
{
    const float* x   = (const float*)d_in[0];
    const float* w3  = (const float*)d_in[1];
    const float* b3  = (const float*)d_in[2];
    const float* g1  = (const float*)d_in[3];
    const float* be1 = (const float*)d_in[4];
    const float* m1  = (const float*)d_in[5];
    const float* v1  = (const float*)d_in[6];
    const float* wa1 = (const float*)d_in[7];
    const float* ba1 = (const float*)d_in[8];
    const float* g2  = (const float*)d_in[9];
    const float* be2 = (const float*)d_in[10];
    const float* m2  = (const float*)d_in[11];
    const float* v2  = (const float*)d_in[12];
    const float* wa2 = (const float*)d_in[13];
    const float* ba2 = (const float*)d_in[14];

    unsigned char* ws = (unsigned char*)d_ws;
    unsigned short* w3T   = (unsigned short*)(ws);
    unsigned short* wa1T  = (unsigned short*)(ws + 131072);
    unsigned short* wa2T  = (unsigned short*)(ws + 147456);
    float*          b_a1p = (float*)(ws + 163840);
    float*          b_a2p = (float*)(ws + 163968);

    hipLaunchKernelGGL(prep_kernel, dim3(97), dim3(256), 0, stream,
                       w3, g1, be1, m1, v1, wa1, ba1, g2, be2, m2, v2, wa2, ba2,
                       w3T, wa1T, wa2T, b_a1p, b_a2p);
    hipLaunchKernelGGL(fused_kernel, dim3(1024), dim3(256), 0, stream,
                       x, b3, w3T, wa1T, wa2T, b_a1p, b_a2p, (float*)d_out);
}

// Round 2
// 78.930 us; speedup vs baseline: 1.4105x; 1.4105x over previous
//
#include <hip/hip_runtime.h>

#define EPS 1e-3f

typedef float f32x4 __attribute__((ext_vector_type(4)));
typedef float f4    __attribute__((ext_vector_type(4)));
typedef short short8 __attribute__((ext_vector_type(8)));

__device__ __forceinline__ unsigned short f2bf(float f) {
    unsigned u = __float_as_uint(f);
    u += 0x7FFFu + ((u >> 16) & 1u);   // round-to-nearest-even
    return (unsigned short)(u >> 16);
}
__device__ __forceinline__ float bf2f(unsigned s) {
    return __uint_as_float(s << 16);
}

// ---------------------------------------------------------------------------
// Prep: fold BN1/BN2 into attention weights, transpose all weights to bf16
// ---------------------------------------------------------------------------
__global__ void prep_kernel(const float* __restrict__ w3,
                            const float* __restrict__ g1, const float* __restrict__ be1,
                            const float* __restrict__ m1, const float* __restrict__ v1,
                            const float* __restrict__ wa1, const float* __restrict__ ba1,
                            const float* __restrict__ g2, const float* __restrict__ be2,
                            const float* __restrict__ m2, const float* __restrict__ v2,
                            const float* __restrict__ wa2, const float* __restrict__ ba2,
                            unsigned short* __restrict__ w3T,
                            unsigned short* __restrict__ wa1T,
                            unsigned short* __restrict__ wa2T,
                            float* __restrict__ b_a1p, float* __restrict__ b_a2p)
{
    const int blk = blockIdx.x;
    const int tid = threadIdx.x;
    if (blk < 64) {
        #pragma unroll
        for (int i = 0; i < 4; ++i) {
            int f = blk * 4 + i;
            w3T[f * 256 + tid] = f2bf(w3[tid * 256 + f]);
        }
    } else if (blk < 96) {
        int a = blk - 64;
        int c = tid;
        float s1 = rsqrtf(v1[c] + EPS) * g1[c];
        float wv = wa1[c * 32 + a];
        wa1T[a * 256 + c] = f2bf(wv * s1);
        float part = (be1[c] - m1[c] * s1) * wv;
        __shared__ float red[4];
        #pragma unroll
        for (int off = 32; off > 0; off >>= 1) part += __shfl_down(part, off);
        if ((tid & 63) == 0) red[tid >> 6] = part;
        __syncthreads();
        if (tid == 0) b_a1p[a] = ba1[a] + red[0] + red[1] + red[2] + red[3];
    } else {
        int f = tid;
        float acc = ba2[f];
        #pragma unroll
        for (int a = 0; a < 32; ++a) {
            float s2 = rsqrtf(v2[a] + EPS) * g2[a];
            float wv = wa2[a * 256 + f];
            wa2T[f * 32 + a] = f2bf(wv * s2);
            acc += (be2[a] - m2[a] * s2) * wv;
        }
        b_a2p[f] = acc;
    }
}

// ---------------------------------------------------------------------------
// Fused main kernel. One block = one image row (b,h): 64 pixels, 256 ch.
// 8 waves: waves 0-3 = attention path (16 px each), waves 4-7 = main GEMM
// (64 f-channels each, all 64 px).  LDS 64 KB:
//   xbf [0,32768)      : x row bf16 [64 px][256 c], XOR-swizzled
//   rs  [32768,65536)   : 3x3 box-sum bf16, same layout
//   after role phase both regions are overwritten by s (f32 [64 px][256 f]).
// MFMA operand order: mfma(w_frag, x_frag, acc) -> C[f][px], col(lane&15)=px,
// row(lkg*4+r)=f -> each lane holds 4 consecutive channels of one pixel.
// ---------------------------------------------------------------------------
__global__ __launch_bounds__(512, 4)
void fused_kernel(const float* __restrict__ x, const float* __restrict__ b3,
                  const unsigned short* __restrict__ w3T,
                  const unsigned short* __restrict__ wa1T,
                  const unsigned short* __restrict__ wa2T,
                  const float* __restrict__ b_a1p, const float* __restrict__ b_a2p,
                  float* __restrict__ out)
{
    __shared__ __align__(16) unsigned char lds[65536];

    const int tid = threadIdx.x;
    const int bid = blockIdx.x;
    // XCD-aware swizzle: 1024 blocks, 8 XCDs -> 128 consecutive rows per XCD
    const int swz = (bid & 7) * 128 + (bid >> 3);
    const int b = swz >> 6;
    const int h = swz & 63;

    const float* xrow = x + ((size_t)(b * 64 + h) * 64) * 256;
    const bool hm = (h > 0), hp = (h < 63);
    const f4* p0 = (const f4*)xrow;
    const f4* pm = (const f4*)(xrow - 64 * 256);
    const f4* pp = (const f4*)(xrow + 64 * 256);
    const f4 zero4 = {0.f, 0.f, 0.f, 0.f};

    // ---------------- phase 0: stage x row (bf16) + vertical 3-row sum ------
    #pragma unroll
    for (int j = 0; j < 8; ++j) {
        int v  = tid + j * 512;        // float4 index within the row (0..4095)
        int w  = v >> 6;
        int c4 = v & 63;
        f4 a0 = p0[v];
        f4 am = hm ? pm[v] : zero4;
        f4 ap = hp ? pp[v] : zero4;
        unsigned cb   = (unsigned)c4 * 8u;
        unsigned addr = (unsigned)w * 512u + (cb ^ (((unsigned)w & 7u) << 4));
        uint2 pk;
        pk.x = (unsigned)f2bf(a0.x) | ((unsigned)f2bf(a0.y) << 16);
        pk.y = (unsigned)f2bf(a0.z) | ((unsigned)f2bf(a0.w) << 16);
        *(uint2*)(lds + addr) = pk;
        f4 s = a0 + am + ap;
        uint2 pr;
        pr.x = (unsigned)f2bf(s.x) | ((unsigned)f2bf(s.y) << 16);
        pr.y = (unsigned)f2bf(s.z) | ((unsigned)f2bf(s.w) << 16);
        *(uint2*)(lds + 32768 + addr) = pr;
    }
    __syncthreads();

    // ---------------- phase 0.5: horizontal 3-tap sum in place -------------
    {
        const int w05 = tid >> 3;      // pixel 0..63
        const int cs  = tid & 7;       // channel eighth
        uint2 tv[8];
        #pragma unroll
        for (int j = 0; j < 8; ++j) {
            int c4 = cs * 8 + j;
            unsigned cb = (unsigned)c4 * 8u;
            f4 sum = zero4;
            #pragma unroll
            for (int dw = -1; dw <= 1; ++dw) {
                int rw = w05 + dw;
                if (rw >= 0 && rw < 64) {
                    unsigned ad = 32768u + (unsigned)rw * 512u +
                                  (cb ^ (((unsigned)rw & 7u) << 4));
                    uint2 q = *(const uint2*)(lds + ad);
                    sum.x += bf2f(q.x & 0xffffu);
                    sum.y += bf2f(q.x >> 16);
                    sum.z += bf2f(q.y & 0xffffu);
                    sum.w += bf2f(q.y >> 16);
                }
            }
            uint2 pk;
            pk.x = (unsigned)f2bf(sum.x) | ((unsigned)f2bf(sum.y) << 16);
            pk.y = (unsigned)f2bf(sum.z) | ((unsigned)f2bf(sum.w) << 16);
            tv[j] = pk;
        }
        __syncthreads();
        #pragma unroll
        for (int j = 0; j < 8; ++j) {
            int c4 = cs * 8 + j;
            unsigned cb = (unsigned)c4 * 8u;
            unsigned ad = 32768u + (unsigned)w05 * 512u +
                          (cb ^ (((unsigned)w05 & 7u) << 4));
            *(uint2*)(lds + ad) = tv[j];
        }
        __syncthreads();
    }

    const int wv   = tid >> 6;
    const int lane = tid & 63;
    const int cl   = lane & 15;
    const int lkg  = lane >> 4;

    f32x4 att[16];          // attention waves: aw (f32, stays in registers)
    f32x4 accs[4][4];       // main waves: s accumulators [ft][pt]

    if (wv < 4) {
        // ================= attention waves: 16 px each =====================
        const int pxb  = wv * 16;
        const int arow = pxb + cl;
        const unsigned abase = (unsigned)arow * 512u;
        const unsigned aswz  = ((unsigned)arow & 7u) << 4;

        // --- GEMM1: a1 = relu(x_bn @ wa1') ; C col = a, row = px -----------
        f32x4 acc1[2];
        acc1[0] = (f32x4){0,0,0,0};
        acc1[1] = (f32x4){0,0,0,0};
        #pragma unroll
        for (int kk = 0; kk < 8; ++kk) {
            unsigned cb = (unsigned)kk * 64u + (unsigned)lkg * 16u;
            short8 afr = *(const short8*)(lds + abase + (cb ^ aswz));
            #pragma unroll
            for (int t = 0; t < 2; ++t) {
                short8 bfr = *(const short8*)(wa1T + ((t * 16 + cl) * 256 + kk * 32 + lkg * 8));
                acc1[t] = __builtin_amdgcn_mfma_f32_16x16x32_bf16(afr, bfr, acc1[t], 0, 0, 0);
            }
        }
        // stash a1 bf16 in this wave's own xbf rows, pitch 40 shorts (80 B)
        const unsigned a1base = (unsigned)(pxb * 512);
        #pragma unroll
        for (int t = 0; t < 2; ++t) {
            int a = t * 16 + cl;
            float bb = b_a1p[a];
            #pragma unroll
            for (int r = 0; r < 4; ++r) {
                float vv = acc1[t][r] + bb;
                vv = vv > 0.f ? vv : 0.f;
                int pxl = lkg * 4 + r;
                *(unsigned short*)(lds + a1base + pxl * 80 + a * 2) = f2bf(vv);
            }
        }
        asm volatile("s_waitcnt lgkmcnt(0)" ::: "memory");
        __builtin_amdgcn_sched_barrier(0);

        // --- GEMM2 (swapped): att[f][px], A = wa2T rows f, B = a1 ----------
        short8 a1f = *(const short8*)(lds + a1base + cl * 80 + lkg * 16);
        #pragma unroll
        for (int t = 0; t < 16; ++t) {
            short8 a2w = *(const short8*)(wa2T + ((t * 16 + cl) * 32 + lkg * 8));
            f32x4 z = {0,0,0,0};
            att[t] = __builtin_amdgcn_mfma_f32_16x16x32_bf16(a2w, a1f, z, 0, 0, 0);
        }
        // bias + relu : lane holds f = t*16 + lkg*4 + r at pixel px = pxb+cl
        #pragma unroll
        for (int t = 0; t < 16; ++t) {
            f4 bb = *(const f4*)(b_a2p + t * 16 + lkg * 4);
            #pragma unroll
            for (int r = 0; r < 4; ++r) {
                float vv = att[t][r] + bb[r];
                att[t][r] = vv > 0.f ? vv : 0.f;
            }
        }
        // softmax over 256 channels: 64 in-lane + lanes {cl,cl+16,cl+32,cl+48}
        float mx = att[0][0];
        #pragma unroll
        for (int t = 0; t < 16; ++t)
            #pragma unroll
            for (int r = 0; r < 4; ++r) mx = fmaxf(mx, att[t][r]);
        mx = fmaxf(mx, __shfl_xor(mx, 16));
        mx = fmaxf(mx, __shfl_xor(mx, 32));
        float sm = 0.f;
        #pragma unroll
        for (int t = 0; t < 16; ++t)
            #pragma unroll
            for (int r = 0; r < 4; ++r) {
                float e = __expf(att[t][r] - mx);
                att[t][r] = e;
                sm += e;
            }
        sm += __shfl_xor(sm, 16);
        sm += __shfl_xor(sm, 32);
        float inv = 1.f / sm;
        #pragma unroll
        for (int t = 0; t < 16; ++t)
            #pragma unroll
            for (int r = 0; r < 4; ++r) att[t][r] *= inv;
    } else {
        // ================= main waves: 64 f-channels, all 64 px ============
        const int wu = wv - 4;
        const int F0 = wu * 64;
        #pragma unroll
        for (int ft = 0; ft < 4; ++ft)
            #pragma unroll
            for (int pt = 0; pt < 4; ++pt) accs[ft][pt] = (f32x4){0,0,0,0};

        for (int kk = 0; kk < 8; ++kk) {
            short8 afr[4];
            #pragma unroll
            for (int ft = 0; ft < 4; ++ft)
                afr[ft] = *(const short8*)(w3T + ((F0 + ft * 16 + cl) * 256 + kk * 32 + lkg * 8));
            short8 bfr[4];
            #pragma unroll
            for (int pt = 0; pt < 4; ++pt) {
                int px = pt * 16 + cl;
                unsigned cb = (unsigned)kk * 64u + (unsigned)lkg * 16u;
                bfr[pt] = *(const short8*)(lds + 32768u + (unsigned)px * 512u +
                                           (cb ^ (((unsigned)px & 7u) << 4)));
            }
            #pragma unroll
            for (int ft = 0; ft < 4; ++ft)
                #pragma unroll
                for (int pt = 0; pt < 4; ++pt)
                    accs[ft][pt] = __builtin_amdgcn_mfma_f32_16x16x32_bf16(afr[ft], bfr[pt], accs[ft][pt], 0, 0, 0);
        }
    }

    __syncthreads();   // attention: aw done (in regs); main: all rs/xbf reads done

    if (wv >= 4) {
        // main waves: s += cnt*b3, write s f32 into LDS [px][256 f] (64 KB)
        const int wu = wv - 4;
        const int F0 = wu * 64;
        const int rh = (h == 0 || h == 63) ? 2 : 3;
        #pragma unroll
        for (int ft = 0; ft < 4; ++ft) {
            int f0 = F0 + ft * 16 + lkg * 4;
            f4 b3v = *(const f4*)(b3 + f0);
            #pragma unroll
            for (int pt = 0; pt < 4; ++pt) {
                int px = pt * 16 + cl;
                float cnt = (float)(rh * ((px == 0 || px == 63) ? 2 : 3));
                f4 sv;
                #pragma unroll
                for (int r = 0; r < 4; ++r) sv[r] = accs[ft][pt][r] + cnt * b3v[r];
                unsigned ad = (unsigned)px * 1024u +
                              (((unsigned)f0 * 4u) ^ (((unsigned)px & 7u) << 4));
                *(f4*)(lds + ad) = sv;
            }
        }
    }

    __syncthreads();

    if (wv < 4) {
        // attention waves: out = aw * s, coalesced dwordx4 stores
        const int pxb = wv * 16;
        const int px  = pxb + cl;
        const size_t obase = ((size_t)(b * 64 + h) * 64 + px) * 256;
        #pragma unroll
        for (int t = 0; t < 16; ++t) {
            int f0 = t * 16 + lkg * 4;
            unsigned ad = (unsigned)px * 1024u +
                          (((unsigned)f0 * 4u) ^ (((unsigned)px & 7u) << 4));
            f4 sv = *(const f4*)(lds + ad);
            f4 o;
            #pragma unroll
            for (int r = 0; r < 4; ++r) o[r] = att[t][r] * sv[r];
            *(f4*)(out + obase + f0) = o;
        }
    }
}

extern "C" void kernel_launch(void* const* d_in, const int* in_sizes, int n_in,
                              void* d_out, int out_size, void* d_ws, size_t ws_size,
                              hipStream_t stream)
{
    const float* x   = (const float*)d_in[0];
    const float* w3  = (const float*)d_in[1];
    const float* b3  = (const float*)d_in[2];
    const float* g1  = (const float*)d_in[3];
    const float* be1 = (const float*)d_in[4];
    const float* m1  = (const float*)d_in[5];
    const float* v1  = (const float*)d_in[6];
    const float* wa1 = (const float*)d_in[7];
    const float* ba1 = (const float*)d_in[8];
    const float* g2  = (const float*)d_in[9];
    const float* be2 = (const float*)d_in[10];
    const float* m2  = (const float*)d_in[11];
    const float* v2  = (const float*)d_in[12];
    const float* wa2 = (const float*)d_in[13];
    const float* ba2 = (const float*)d_in[14];

    unsigned char* ws = (unsigned char*)d_ws;
    unsigned short* w3T   = (unsigned short*)(ws);
    unsigned short* wa1T  = (unsigned short*)(ws + 131072);
    unsigned short* wa2T  = (unsigned short*)(ws + 147456);
    float*          b_a1p = (float*)(ws + 163840);
    float*          b_a2p = (float*)(ws + 163968);

    hipLaunchKernelGGL(prep_kernel, dim3(97), dim3(256), 0, stream,
                       w3, g1, be1, m1, v1, wa1, ba1, g2, be2, m2, v2, wa2, ba2,
                       w3T, wa1T, wa2T, b_a1p, b_a2p);
    hipLaunchKernelGGL(fused_kernel, dim3(1024), dim3(512), 0, stream,
                       x, b3, w3T, wa1T, wa2T, b_a1p, b_a2p, (float*)d_out);
}